// Round 5
// baseline (184.054 us; speedup 1.0000x reference)
//
#include <hip/hip_runtime.h>
#include <stdint.h>

// Problem constants (from reference setup_inputs)
#define BNUM  8192
#define LROWS 32
#define MLAB  32
#define CCLS  96
#define SPB   2                   // samples per block = one wave, one per 32-lane half
#define NBLK  (BNUM/SPB)          // 4096 blocks
#define PSTR  97                  // padded LDS row stride in floats (+1 dword: bank-conflict-free)
#define SSTR  (LROWS*PSTR)        // 3104 floats per sample
#define XS_F  (SPB*SSTR)          // 6208 floats of x-stage
#define LP_F  XS_F                // lse/pred region: 2 floats per row, 128 floats
#define TOT_F (XS_F + SPB*LROWS*2) // 6336 floats = 25,344 B -> 6 blocks/CU

// Design (round 5): kill the strided global pattern.
//  Stage:  24 x global dwordx4, PERFECTLY COALESCED (lane i -> contiguous 16 B,
//          1 KB/instr — the m13 6.3 TB/s pattern), scattered into LDS with
//          +1-dword padded rows (stride 97 floats). ds_write_b32 only (odd
//          stride forbids b64/b128 merging — alignment unprovable, so the
//          compiler keeps 4-B ops; write conflicts ~3-way, near-free).
//  P1:     lane u reads row u of its half's sample from LDS: fixed k, banks
//          (97u+k)%32 = (u+k)%32 -> all 32 lanes distinct banks; halves are
//          +3104 (== 0 mod 32) -> exact 2-way, which is free. Scan math is
//          BIT-IDENTICAL to the verified kernel (same 4x24 block grouping,
//          ascending order, strict '>', same sumexp association).
//  B:      DP wavefront, DPP wave_shr:1 chain (HW-verified exact, r2).
//          ce computed inline from LDS (lse, pred from lpS; x[i-1][lab] from
//          x-stage) — ceTab and P3 deleted. Operand addresses depend only on
//          (d,lane): off the serial chain, prefetched across unroll-4.
//  1 wave/block -> zero barriers; same-wave DS producer/consumer is in-order
//  (drained with lgkmcnt(0)). 4096 blocks at 6/CU run in ~2.7 staggered
//  generations, overlapping one generation's compute with the next's loads.
__device__ __forceinline__ int dpp_wshr1_i32(int v) {
    // dpp_ctrl 0x138 = wave_shr:1; lanes 0/32 bound_ctrl zeros are overridden
    // by the analytic column-0 injection below (same semantics as width-64
    // __shfl_up, proven bit-exact on HW in round 2).
    return __builtin_amdgcn_update_dpp(0, v, 0x138, 0xF, 0xF, true);
}
__device__ __forceinline__ float dpp_wshr1_f32(float v) {
    return __int_as_float(
        __builtin_amdgcn_update_dpp(0, __float_as_int(v), 0x138, 0xF, 0xF, true));
}

__global__ __launch_bounds__(64, 2) void editloss_main(
    const float* __restrict__ x, const int* __restrict__ y,
    float* __restrict__ partial_sum, float* __restrict__ partial_cnt)
{
    __shared__ float S[TOT_F];

    const int lane = threadIdx.x;        // 0..63
    const int g    = lane >> 5;          // which sample of the wave
    const int u    = lane & 31;          // slot within 32-lane half
    const int sb0  = blockIdx.x * SPB;

    const float* gx    = x + (size_t)sb0 * (LROWS * CCLS);   // 2 samples, contiguous
    const int    lab_u = y[(sb0 + g) * MLAB + u];

    // ---------- Stage: coalesced global -> padded LDS ----------------------
#pragma unroll
    for (int i = 0; i < 24; ++i) {
        const int    f = i * 256 + lane * 4;         // flat float idx, 0..6140
        const float4 v = *(const float4*)(gx + f);   // lane-contiguous 16 B
        const int samp = (f >= 3072) ? 1 : 0;
        const int fs   = f - samp * 3072;
        const int n    = fs >> 5;                    // 0..95
        const int row  = (n * 171) >> 9;             // exact n/3 for n<512
        const int col  = fs - row * 96;              // 0..92, multiple of 4
        float* p = &S[samp * SSTR + row * PSTR + col];
        p[0] = v.x; p[1] = v.y; p[2] = v.z; p[3] = v.w;
    }
    asm volatile("s_waitcnt lgkmcnt(0)" ::: "memory");   // same-wave, in-order DS

    // ---------- P1: lane-per-row argmax + logsumexp from LDS ---------------
    {
        const float* rp = &S[g * SSTR + u * PSTR];
        float bmax[4]; int bidx[4]; float bsum[4];
#pragma unroll
        for (int c = 0; c < 4; ++c) { bmax[c] = -1e30f; bidx[c] = 0; bsum[c] = 0.f; }
#pragma unroll
        for (int t = 0; t < 24; ++t) {               // identical order/grouping
            const int c = t / 6;                     //   to the verified kernel
            const float v0 = rp[t * 4 + 0];
            const float v1 = rp[t * 4 + 1];
            const float v2 = rp[t * 4 + 2];
            const float v3 = rp[t * 4 + 3];
            const int base = t * 4;
            if (v0 > bmax[c]) { bmax[c] = v0; bidx[c] = base + 0; }
            if (v1 > bmax[c]) { bmax[c] = v1; bidx[c] = base + 1; }
            if (v2 > bmax[c]) { bmax[c] = v2; bidx[c] = base + 2; }
            if (v3 > bmax[c]) { bmax[c] = v3; bidx[c] = base + 3; }
            bsum[c] += __expf(v0) + __expf(v1) + __expf(v2) + __expf(v3);
        }
        float m = bmax[0]; int idx = bidx[0];
#pragma unroll
        for (int c = 1; c < 4; ++c)                  // strict '>': first occurrence
            if (bmax[c] > m) { m = bmax[c]; idx = bidx[c]; }
        const float lse = __logf((bsum[0] + bsum[1]) + (bsum[2] + bsum[3]));
        S[LP_F + (g * 32 + u) * 2 + 0] = lse;
        S[LP_F + (g * 32 + u) * 2 + 1] = (float)idx;
    }
    asm volatile("s_waitcnt lgkmcnt(0)" ::: "memory");

    // ---------- Phase B: fused DP wavefront (DPP chain, inline ce) ---------
    // lane u = column j = u+1 (column 0 analytic). Carried: D|cnt<<8, ce-sum.
    const int   j      = u + 1;
    const float fl     = (float)lab_u;
    const int   xbase  = g * SSTR + lab_u;           // + ic*PSTR
    const int   lpbase = LP_F + g * 64;              // + ic*2
    int   prevW = 0;   float prevCE = 0.f;
    int   diagW = 0;   float diagCE = 0.f;
#pragma unroll 4
    for (int d = 1; d <= LROWS + MLAB; ++d) {
        const int   lWs  = dpp_wshr1_i32(prevW);     // (i, j-1)
        const float lCEs = dpp_wshr1_f32(prevCE);
        const int i  = d - j;
        const int ic = min(max(i - 1, 0), LROWS - 1);
        const float xg  = S[xbase  + ic * PSTR];     // x[i-1, lab_u] — off-chain
        const float lse = S[lpbase + ic * 2 + 0];    // {lse,pred} — off-chain
        const float prf = S[lpbase + ic * 2 + 1];
        // column 0 analytic: D(i,0)=i, cnt=0, ce=0
        const int   lW  = (u == 0) ? max(i, 0)     : lWs;
        const float lCE = (u == 0) ? 0.f           : lCEs;
        const int   dW  = (u == 0) ? max(i - 1, 0) : diagW;
        const float dCE = (u == 0) ? 0.f           : diagCE;
        int curW; float curCE;
        if (i <= 0) {                       // top row: D=j; i<0 lanes inactive
            curW = j; curCE = 0.f;
        } else if (i > LROWS) {             // column finished: hold final value
            curW = prevW; curCE = prevCE;
        } else {
            const int uD = prevW & 255, uC = prevW >> 8;
            const int lD = lW & 255,    lC = lW >> 8;
            const int dD = dW & 255,    dC = dW >> 8;
            const float ce = lse - xg;      // strictly > 0
            const int   c  = (prf != fl) ? 1 : 0;
            const int nD = min(min(uD, lD) + 1, dD + c);
            // reference backtrace tie-break: diag > up > left
            const bool dg = (dD + c == nD);
            const bool up = !dg && (uD + 1 == nD);
            int nC; float nCE;
            if (dg)      { nC = dC + 1; nCE = dCE + ce; }
            else if (up) { nC = uC;     nCE = prevCE;   }
            else         { nC = lC;     nCE = lCE;      }
            curW = nD | (nC << 8);
            curCE = nCE;
        }
        diagW = lWs; diagCE = lCEs;         // raw shifted value becomes next diag
        prevW = curW; prevCE = curCE;
    }

    // lanes 31 (g=0) and 63 (g=1) hold cell (32,32) of their samples
    float ps = 0.f, pc = 0.f;
    if (u == 31) {
        const int cnt = prevW >> 8;
        ps = (cnt > 0) ? prevCE / (float)cnt : 0.f;
        pc = (cnt > 0) ? 1.f : 0.f;
    }
    ps += __shfl_down(ps, 32);              // lane 31 += lane 63
    pc += __shfl_down(pc, 32);
    if (lane == 31) {
        partial_sum[blockIdx.x] = ps;
        partial_cnt[blockIdx.x] = pc;
    }
}

__global__ __launch_bounds__(256) void editloss_finalize(
    const float* __restrict__ partial_sum, const float* __restrict__ partial_cnt,
    float* __restrict__ out, int nblocks)
{
    float s = 0.f, c = 0.f;
    for (int k = threadIdx.x; k < nblocks; k += 256) {
        s += partial_sum[k];
        c += partial_cnt[k];
    }
#pragma unroll
    for (int d = 32; d >= 1; d >>= 1) {
        s += __shfl_xor(s, d);
        c += __shfl_xor(c, d);
    }
    __shared__ float ss[4], cc[4];
    const int w = threadIdx.x >> 6, lane = threadIdx.x & 63;
    if (lane == 0) { ss[w] = s; cc[w] = c; }
    __syncthreads();
    if (threadIdx.x == 0) {
        const float S  = ss[0] + ss[1] + ss[2] + ss[3];
        const float C2 = cc[0] + cc[1] + cc[2] + cc[3];
        out[0] = (C2 > 0.f) ? (S / C2) : 0.f;
    }
}

extern "C" void kernel_launch(void* const* d_in, const int* in_sizes, int n_in,
                              void* d_out, int out_size, void* d_ws, size_t ws_size,
                              hipStream_t stream) {
    const float* x = (const float*)d_in[0];
    const int*   y = (const int*)d_in[1];
    // d_in[2]=num_chars, d_in[3]=num_labels: constants L/M in this problem.
    float* out = (float*)d_out;

    float* partial_sum = (float*)d_ws;           // NBLK floats
    float* partial_cnt = partial_sum + NBLK;     // NBLK floats

    editloss_main<<<NBLK, 64, 0, stream>>>(x, y, partial_sum, partial_cnt);
    editloss_finalize<<<1, 256, 0, stream>>>(partial_sum, partial_cnt, out, NBLK);
}

// Round 6
// 163.851 us; speedup vs baseline: 1.1233x; 1.1233x over previous
//
#include <hip/hip_runtime.h>
#include <stdint.h>

// Problem constants (from reference setup_inputs)
#define BNUM  8192
#define LROWS 32
#define MLAB  32
#define CCLS  96
#define WPB   4              // waves per block
#define SPW   2              // samples per wave (one per 32-lane half)
#define SPB   (WPB*SPW)      // 8 samples per block
#define NBLK  (BNUM/SPB)     // 1024 blocks

typedef float f32x4 __attribute__((ext_vector_type(4)));

// Design (round 6): fix the outstanding-bytes starvation.
//  Model (fits r0/r2/r4/r5 measurements): achieved BW ~= in-flight bytes per
//  CU / ~800cy miss latency. Previous kernels kept only ~8 loads in flight
//  per wave (compiler re-interleaved under a 128-VGPR budget) -> 1.4-1.6 TB/s.
//  This round: launch_bounds(256,3) raises the VGPR cap to 168; ALL 24 row
//  loads (va[24], 96 VGPR) AND all 32 P3 gathers (xg[32], 32 VGPR) are issued
//  back-to-back and pinned live with empty asm register constraints so the
//  compiler cannot sink/re-interleave them. One latency stall per wave,
//  ~512 B/lane in flight, 12 waves/CU -> ~6 KB/CU -> ~4.5 TB/s.
//  P1/P3/Phase-B math is BIT-IDENTICAL to the verified r0/r4 kernel.
__device__ __forceinline__ int dpp_wshr1_i32(int v) {
    // dpp_ctrl 0x138 = wave_shr:1; lanes 0/32 bound_ctrl zeros are overridden
    // by the analytic column-0 injection (HW-verified exact, round 2).
    return __builtin_amdgcn_update_dpp(0, v, 0x138, 0xF, 0xF, true);
}
__device__ __forceinline__ float dpp_wshr1_f32(float v) {
    return __int_as_float(
        __builtin_amdgcn_update_dpp(0, __float_as_int(v), 0x138, 0xF, 0xF, true));
}

__global__ __launch_bounds__(256, 3) void editloss_main(
    const float* __restrict__ x, const int* __restrict__ y,
    float* __restrict__ partial_sum, float* __restrict__ partial_cnt)
{
    __shared__ float  ceTab[SPB][LROWS * MLAB];  // 32 KB
    __shared__ float2 lpS[SPB][LROWS];           // 2 KB: {lse, (float)pred}
    __shared__ float  psum[SPB];
    __shared__ float  pcnt[SPB];

    const int w    = threadIdx.x >> 6;
    const int lane = threadIdx.x & 63;
    const int g    = lane >> 5;          // which sample of the wave
    const int u    = lane & 31;          // slot within 32-lane half
    const int s    = w * SPW + g;        // sample slot in block [0,8)
    const int sb   = blockIdx.x * SPB + s;

    const float* xs    = x + (size_t)sb * (LROWS * CCLS);
    const int    lab_u = y[sb * MLAB + u];

    // ---------- Issue ALL global loads back-to-back -------------------------
    const f32x4* rowv = (const f32x4*)(xs + (size_t)u * CCLS);
    f32x4 va[24];
#pragma unroll
    for (int t = 0; t < 24; ++t) va[t] = rowv[t];

    const float* gcol = xs + lab_u;       // x[:, lab_u], row stride CCLS
    float xg[LROWS];
#pragma unroll
    for (int r = 0; r < LROWS; ++r) xg[r] = gcol[r * CCLS];

    // Pin every load result live: forces materialization of all 56 loads
    // before any consumption (compiler cannot re-interleave / shrink the
    // in-flight window). "memory" on the second pin stops load sinking.
    asm volatile("" :
        "+v"(va[0]),  "+v"(va[1]),  "+v"(va[2]),  "+v"(va[3]),
        "+v"(va[4]),  "+v"(va[5]),  "+v"(va[6]),  "+v"(va[7]),
        "+v"(va[8]),  "+v"(va[9]),  "+v"(va[10]), "+v"(va[11]),
        "+v"(va[12]), "+v"(va[13]), "+v"(va[14]), "+v"(va[15]),
        "+v"(va[16]), "+v"(va[17]), "+v"(va[18]), "+v"(va[19]),
        "+v"(va[20]), "+v"(va[21]), "+v"(va[22]), "+v"(va[23]));
    asm volatile("" :
        "+v"(xg[0]),  "+v"(xg[1]),  "+v"(xg[2]),  "+v"(xg[3]),
        "+v"(xg[4]),  "+v"(xg[5]),  "+v"(xg[6]),  "+v"(xg[7]),
        "+v"(xg[8]),  "+v"(xg[9]),  "+v"(xg[10]), "+v"(xg[11]),
        "+v"(xg[12]), "+v"(xg[13]), "+v"(xg[14]), "+v"(xg[15]),
        "+v"(xg[16]), "+v"(xg[17]), "+v"(xg[18]), "+v"(xg[19]),
        "+v"(xg[20]), "+v"(xg[21]), "+v"(xg[22]), "+v"(xg[23]),
        "+v"(xg[24]), "+v"(xg[25]), "+v"(xg[26]), "+v"(xg[27]),
        "+v"(xg[28]), "+v"(xg[29]), "+v"(xg[30]), "+v"(xg[31])
        :: "memory");

    // ---------- P1: lane-per-row argmax + logsumexp (bit-identical math) ----
    {
        float bmax[4]; int bidx[4]; float bsum[4];
#pragma unroll
        for (int c = 0; c < 4; ++c) { bmax[c] = -1e30f; bidx[c] = 0; bsum[c] = 0.f; }
#pragma unroll
        for (int t = 0; t < 24; ++t) {
            const int c = t / 6;                  // compile-time per unrolled t
            const f32x4 v = va[t];
            const int base = t * 4;
            // ascending scan, strict '>' keeps first occurrence
            if (v[0] > bmax[c]) { bmax[c] = v[0]; bidx[c] = base + 0; }
            if (v[1] > bmax[c]) { bmax[c] = v[1]; bidx[c] = base + 1; }
            if (v[2] > bmax[c]) { bmax[c] = v[2]; bidx[c] = base + 2; }
            if (v[3] > bmax[c]) { bmax[c] = v[3]; bidx[c] = base + 3; }
            bsum[c] += __expf(v[0]) + __expf(v[1]) + __expf(v[2]) + __expf(v[3]);
        }
        float m = bmax[0]; int idx = bidx[0];
#pragma unroll
        for (int c = 1; c < 4; ++c)           // strict '>': earlier block wins ties
            if (bmax[c] > m) { m = bmax[c]; idx = bidx[c]; }
        const float lse = __logf((bsum[0] + bsum[1]) + (bsum[2] + bsum[3]));
        lpS[s][u] = make_float2(lse, (float)idx);
    }
    // Same-wave producer/consumer; DS pipe is in-order per wave. Drain to be safe.
    asm volatile("s_waitcnt lgkmcnt(0)" ::: "memory");

    // ---------- P3: ceTab build from pinned registers + lpS ----------------
    {
        const float fl = (float)lab_u;
#pragma unroll
        for (int r = 0; r < LROWS; ++r) {
            const float2 lp = lpS[s][r];      // wave-uniform per half: broadcast
            const float  ce = lp.x - xg[r];   // strictly > 0
            ceTab[s][r * MLAB + u] = (lp.y == fl) ? ce : -ce;
        }
    }
    asm volatile("s_waitcnt lgkmcnt(0)" ::: "memory");

    // ---------- Phase B: fused DP wavefront (DPP-shift chain) ---------------
    // lane u = column j = u+1 (column 0 analytic). Carried: D|cnt<<8, ce-sum.
    const int j = u + 1;
    int   prevW = 0;   float prevCE = 0.f;
    int   diagW = 0;   float diagCE = 0.f;
#pragma unroll 4
    for (int d = 1; d <= LROWS + MLAB; ++d) {
        const int   lWs  = dpp_wshr1_i32(prevW);    // (i, j-1)
        const float lCEs = dpp_wshr1_f32(prevCE);
        const int i = d - j;
        // column 0 analytic: D(i,0)=i, cnt=0, ce=0
        const int   lW  = (u == 0) ? max(i, 0)     : lWs;
        const float lCE = (u == 0) ? 0.f           : lCEs;
        const int   dW  = (u == 0) ? max(i - 1, 0) : diagW;
        const float dCE = (u == 0) ? 0.f           : diagCE;
        int curW; float curCE;
        if (i <= 0) {                       // top row: D=j; i<0 lanes inactive
            curW = j; curCE = 0.f;
        } else if (i > LROWS) {             // column finished: hold final value
            curW = prevW; curCE = prevCE;
        } else {
            const int uD = prevW & 255, uC = prevW >> 8;
            const int lD = lW & 255,    lC = lW >> 8;
            const int dD = dW & 255,    dC = dW >> 8;
            const float ct  = ceTab[s][(i - 1) * MLAB + u];
            const int   c   = (ct < 0.f) ? 1 : 0;
            const int nD = min(min(uD, lD) + 1, dD + c);
            // reference backtrace tie-break: diag > up > left
            const bool dg = (dD + c == nD);
            const bool up = !dg && (uD + 1 == nD);
            int nC; float nCE;
            if (dg)      { nC = dC + 1; nCE = dCE + fabsf(ct); }
            else if (up) { nC = uC;     nCE = prevCE;          }
            else         { nC = lC;     nCE = lCE;             }
            curW = nD | (nC << 8);
            curCE = nCE;
        }
        diagW = lWs; diagCE = lCEs;         // raw shifted value becomes next diag
        prevW = curW; prevCE = curCE;
    }

    // lane u==31 (j=32) holds cell (32,32) after d=64
    if (u == 31) {
        const int cnt = prevW >> 8;
        psum[s] = (cnt > 0) ? prevCE / (float)cnt : 0.f;
        pcnt[s] = (cnt > 0) ? 1.f : 0.f;
    }
    __syncthreads();
    if (threadIdx.x == 0) {
        float ss = 0.f, cc = 0.f;
#pragma unroll
        for (int k = 0; k < SPB; ++k) { ss += psum[k]; cc += pcnt[k]; }
        partial_sum[blockIdx.x] = ss;
        partial_cnt[blockIdx.x] = cc;
    }
}

__global__ __launch_bounds__(256) void editloss_finalize(
    const float* __restrict__ partial_sum, const float* __restrict__ partial_cnt,
    float* __restrict__ out, int nblocks)
{
    float s = 0.f, c = 0.f;
    for (int k = threadIdx.x; k < nblocks; k += 256) {
        s += partial_sum[k];
        c += partial_cnt[k];
    }
#pragma unroll
    for (int d = 32; d >= 1; d >>= 1) {
        s += __shfl_xor(s, d);
        c += __shfl_xor(c, d);
    }
    __shared__ float ss[4], cc[4];
    const int w = threadIdx.x >> 6, lane = threadIdx.x & 63;
    if (lane == 0) { ss[w] = s; cc[w] = c; }
    __syncthreads();
    if (threadIdx.x == 0) {
        const float S  = ss[0] + ss[1] + ss[2] + ss[3];
        const float C2 = cc[0] + cc[1] + cc[2] + cc[3];
        out[0] = (C2 > 0.f) ? (S / C2) : 0.f;
    }
}

extern "C" void kernel_launch(void* const* d_in, const int* in_sizes, int n_in,
                              void* d_out, int out_size, void* d_ws, size_t ws_size,
                              hipStream_t stream) {
    const float* x = (const float*)d_in[0];
    const int*   y = (const int*)d_in[1];
    // d_in[2]=num_chars, d_in[3]=num_labels: constants L/M in this problem.
    float* out = (float*)d_out;

    float* partial_sum = (float*)d_ws;           // NBLK floats
    float* partial_cnt = partial_sum + NBLK;     // NBLK floats

    editloss_main<<<NBLK, 256, 0, stream>>>(x, y, partial_sum, partial_cnt);
    editloss_finalize<<<1, 256, 0, stream>>>(partial_sum, partial_cnt, out, NBLK);
}